// Round 1
// baseline (146.257 us; speedup 1.0000x reference)
//
#include <hip/hip_runtime.h>
#include <hip/hip_bf16.h>

typedef __attribute__((ext_vector_type(8))) short short8;
typedef __attribute__((ext_vector_type(4))) float floatx4;

#define MARGIN 0.3f
static constexpr int N = 8192;   // b*n points
static constexpr int C = 256;    // feature dim

// ---------------- kernel 0: fp32->bf16 convert + workspace init ----------------
__global__ void k_prep(const float* __restrict__ feat, __hip_bfloat16* __restrict__ fb,
                       unsigned* __restrict__ posmax, unsigned* __restrict__ negmin,
                       float* __restrict__ scalars) {
    int i = blockIdx.x * 256 + threadIdx.x;
    if (i < N * C) fb[i] = __float2bfloat16(feat[i]);
    if (i < N) { posmax[i] = 0u; negmin[i] = 0x7f800000u; /* +inf */ }
    if (i < 8) scalars[i] = 0.f;
}

// ---------------- kernel 1: per-row squared norms (one wave per row) -----------
__global__ void k_sq(const float* __restrict__ feat, float* __restrict__ sq) {
    int gid = blockIdx.x * 256 + threadIdx.x;
    int row = gid >> 6;
    int lane = threadIdx.x & 63;
    const float4* p = (const float4*)(feat + (size_t)row * C);
    float4 v = p[lane];                    // 64 lanes x 4 floats = 256
    float s = v.x * v.x + v.y * v.y + v.z * v.z + v.w * v.w;
#pragma unroll
    for (int off = 32; off; off >>= 1) s += __shfl_xor(s, off);
    if (lane == 0) sq[row] = s;
}

// ---------------- kernel 2: mse + dr (tiny reductions) -------------------------
__global__ void k_small(const float* __restrict__ s0, const float* __restrict__ s1,
                        const float* __restrict__ s2, const float* __restrict__ g,
                        const float* __restrict__ e0, const float* __restrict__ e1,
                        const float* __restrict__ l0, const float* __restrict__ l1,
                        float* __restrict__ scalars) {
    const int E = 64 * 1024;
    int tid = blockIdx.x * 256 + threadIdx.x;
    int nth = gridDim.x * 256;
    float acc = 0.f;
    for (int i = tid; i < E; i += nth) acc += fabsf(e0[i] - l0[i]) * (1.f / E);
    for (int i = tid; i < E; i += nth) acc += fabsf(e1[i] - l1[i]) * (1.f / E);
    if (tid < 192) {
        int k = tid >> 6, i = tid & 63;
        const float* s = (k == 0) ? s0 : ((k == 1) ? s1 : s2);
        float d = s[i] - g[i];
        acc += d * d * (1.f / 192.f);
    }
#pragma unroll
    for (int off = 32; off; off >>= 1) acc += __shfl_xor(acc, off);
    __shared__ float red[4];
    int lane = threadIdx.x & 63, w = threadIdx.x >> 6;
    if (lane == 0) red[w] = acc;
    __syncthreads();
    if (threadIdx.x == 0)
        atomicAdd(&scalars[0], red[0] + red[1] + red[2] + red[3]);
}

// ---------------- kernel 3: pairwise d2 via bf16 MFMA + hardest mining ---------
// Grid: (i_tile 0..63) x (j_chunk 0..7). Block 256 thr = 4 waves (2x2 quadrants
// of a 128x128 output tile). Labels have period 128, so within any 128-aligned
// tile: positive pairs == tile diagonal (ii==jj), negatives == off-diagonal.
__global__ __launch_bounds__(256, 2)
void k_trip(const __hip_bfloat16* __restrict__ fb, const float* __restrict__ sq,
            unsigned* __restrict__ posmax, unsigned* __restrict__ negmin) {
    // XOR-swizzled LDS: granule (row,g) of 8 bf16 stored at row*16 + (g ^ (row&7)).
    // -> b128 reads by 16 lanes of a quad hit distinct bank groups (conflict-free).
    __shared__ uint4 As[2048];   // 128 rows x 128 bf16 (one 128-wide K chunk)
    __shared__ uint4 Bs[2048];

    const int t = threadIdx.x;
    const int ib = (blockIdx.x >> 3) * 128;   // i-tile base row
    const int jc = (blockIdx.x & 7) * 1024;   // j-chunk base (8 tiles of 128)
    const int w = t >> 6, lane = t & 63;
    const int wi = w >> 1, wj = w & 1;        // wave quadrant
    const int quad = lane >> 4, l15 = lane & 15;

    float si[16];                              // ||x_i||^2 for this lane's 16 acc rows
#pragma unroll
    for (int q = 0; q < 16; ++q)
        si[q] = sq[ib + wi * 64 + (q >> 2) * 16 + quad * 4 + (q & 3)];

    float negm[16], posm[16];                  // running per-row min(neg d2), max(pos d2)
#pragma unroll
    for (int q = 0; q < 16; ++q) { negm[q] = INFINITY; posm[q] = 0.f; }

    for (int jt = 0; jt < 8; ++jt) {
        const int jb = jc + jt * 128;
        floatx4 acc[4][4];
#pragma unroll
        for (int ti = 0; ti < 4; ++ti)
#pragma unroll
            for (int tj = 0; tj < 4; ++tj)
                acc[ti][tj] = (floatx4){0.f, 0.f, 0.f, 0.f};

#pragma unroll
        for (int kc = 0; kc < 2; ++kc) {       // K = 256 in 2 chunks of 128
            __syncthreads();                   // prior-tile LDS reads done
#pragma unroll
            for (int it = 0; it < 8; ++it) {   // stage 2048 granules w/ 256 threads
                int fg = it * 256 + t;
                int row = fg >> 4, g = fg & 15;
                int dst = row * 16 + (g ^ (row & 7));
                As[dst] = ((const uint4*)(fb + (size_t)(ib + row) * C + kc * 128))[g];
                Bs[dst] = ((const uint4*)(fb + (size_t)(jb + row) * C + kc * 128))[g];
            }
            __syncthreads();
#pragma unroll
            for (int k1 = 0; k1 < 4; ++k1) {   // 4 x K=32 MFMA steps
                short8 a[4], b[4];
                int g = k1 * 4 + quad;
#pragma unroll
                for (int ti = 0; ti < 4; ++ti) {
                    int row = wi * 64 + ti * 16 + l15;
                    a[ti] = *(const short8*)&As[row * 16 + (g ^ (row & 7))];
                }
#pragma unroll
                for (int tj = 0; tj < 4; ++tj) {
                    int row = wj * 64 + tj * 16 + l15;
                    b[tj] = *(const short8*)&Bs[row * 16 + (g ^ (row & 7))];
                }
#pragma unroll
                for (int ti = 0; ti < 4; ++ti)
#pragma unroll
                    for (int tj = 0; tj < 4; ++tj)
                        acc[ti][tj] = __builtin_amdgcn_mfma_f32_16x16x32_bf16(
                            a[ti], b[tj], acc[ti][tj], 0, 0, 0);
            }
        }

        // epilogue: d2 = si + sj - 2*dot; diagonal => positive (or self), else negative
#pragma unroll
        for (int tj = 0; tj < 4; ++tj) {
            int jjl = wj * 64 + tj * 16 + l15;       // local col (0..127)
            float sj = sq[jb + jjl];
#pragma unroll
            for (int ti = 0; ti < 4; ++ti) {
#pragma unroll
                for (int r = 0; r < 4; ++r) {
                    int iil = wi * 64 + ti * 16 + quad * 4 + r;   // local row (0..127)
                    float d2 = fmaxf(fmaf(-2.f, acc[ti][tj][r], si[ti * 4 + r] + sj), 0.f);
                    bool diag = (iil == jjl);
                    negm[ti * 4 + r] = fminf(negm[ti * 4 + r], diag ? INFINITY : d2);
                    posm[ti * 4 + r] = fmaxf(posm[ti * 4 + r],
                                             (diag && ib != jb) ? d2 : 0.f);
                }
            }
        }
    }

    // reduce across the 16 lanes of each quad (they hold the row's 64 columns),
    // then one atomic per row per block. Nonneg floats: uint-bit compare == float compare.
#pragma unroll
    for (int q = 0; q < 16; ++q) {
        float nm = negm[q], pm = posm[q];
#pragma unroll
        for (int off = 1; off < 16; off <<= 1) {
            nm = fminf(nm, __shfl_xor(nm, off));
            pm = fmaxf(pm, __shfl_xor(pm, off));
        }
        if (l15 == 0) {
            int row = ib + wi * 64 + (q >> 2) * 16 + quad * 4 + (q & 3);
            atomicMin(&negmin[row], __float_as_uint(nm));
            atomicMax(&posmax[row], __float_as_uint(pm));
        }
    }
}

// ---------------- kernel 4: final combine ---------------------------------------
__global__ void k_final(const unsigned* __restrict__ posmax, const unsigned* __restrict__ negmin,
                        const float* __restrict__ scalars, float* __restrict__ out) {
    float acc = 0.f;
    for (int i = threadIdx.x; i < N; i += 1024) {
        float hp = sqrtf(__uint_as_float(posmax[i]));
        float hn = sqrtf(__uint_as_float(negmin[i]));
        acc += fmaxf(hp - hn + MARGIN, 0.f);
    }
#pragma unroll
    for (int off = 32; off; off >>= 1) acc += __shfl_xor(acc, off);
    __shared__ float red[16];
    if ((threadIdx.x & 63) == 0) red[threadIdx.x >> 6] = acc;
    __syncthreads();
    if (threadIdx.x == 0) {
        float tsum = 0.f;
#pragma unroll
        for (int i = 0; i < 16; ++i) tsum += red[i];
        out[0] = scalars[0] + tsum * (1.f / N);
    }
}

extern "C" void kernel_launch(void* const* d_in, const int* in_sizes, int n_in,
                              void* d_out, int out_size, void* d_ws, size_t ws_size,
                              hipStream_t stream) {
    const float* feat = (const float*)d_in[0];
    const float* gt   = (const float*)d_in[1];
    const float* s0   = (const float*)d_in[2];
    const float* s1   = (const float*)d_in[3];
    const float* s2   = (const float*)d_in[4];
    const float* e0   = (const float*)d_in[5];
    const float* e1   = (const float*)d_in[6];
    const float* l0   = (const float*)d_in[7];
    const float* l1   = (const float*)d_in[8];
    float* out = (float*)d_out;

    char* ws = (char*)d_ws;
    __hip_bfloat16* fb = (__hip_bfloat16*)ws;                       // N*C*2 = 4 MB
    float*    sq      = (float*)(ws + (size_t)N * C * 2);           // 32 KB
    unsigned* posmax  = (unsigned*)(ws + (size_t)N * C * 2 + N * 4);
    unsigned* negmin  = (unsigned*)(ws + (size_t)N * C * 2 + N * 8);
    float*    scalars = (float*)(ws + (size_t)N * C * 2 + N * 12);

    k_prep<<<(N * C + 255) / 256, 256, 0, stream>>>(feat, fb, posmax, negmin, scalars);
    k_sq<<<N / 4, 256, 0, stream>>>(feat, sq);
    k_small<<<64, 256, 0, stream>>>(s0, s1, s2, gt, e0, e1, l0, l1, scalars);
    k_trip<<<512, 256, 0, stream>>>(fb, sq, posmax, negmin);
    k_final<<<1, 1024, 0, stream>>>(posmax, negmin, scalars, out);
}

// Round 2
// 132.540 us; speedup vs baseline: 1.1035x; 1.1035x over previous
//
#include <hip/hip_runtime.h>
#include <hip/hip_bf16.h>

typedef __attribute__((ext_vector_type(8))) short short8;
typedef __attribute__((ext_vector_type(4))) float floatx4;

#define MARGIN 0.3f
static constexpr int N = 8192;   // b*n points
static constexpr int C = 256;    // feature dim

// async 16B global->LDS (dest = wave-uniform base + lane*16)
__device__ __forceinline__ void async16(const void* g, void* l) {
    __builtin_amdgcn_global_load_lds(
        (const __attribute__((address_space(1))) unsigned int*)g,
        (__attribute__((address_space(3))) unsigned int*)l, 16, 0, 0);
}

// ---------------- kernel 0: fp32->bf16 convert + row norms + init --------------
// one wave per row (4 rows / 256-thr block)
__global__ void k_prep_sq(const float* __restrict__ feat, __hip_bfloat16* __restrict__ fb,
                          float* __restrict__ sq, unsigned* __restrict__ posmax,
                          unsigned* __restrict__ negmin, float* __restrict__ scalars) {
    int row = blockIdx.x * 4 + (threadIdx.x >> 6);
    int lane = threadIdx.x & 63;
    float4 v = ((const float4*)feat)[row * 64 + lane];
    union { __hip_bfloat16 h[4]; ushort4 u; } cv;
    cv.h[0] = __float2bfloat16(v.x); cv.h[1] = __float2bfloat16(v.y);
    cv.h[2] = __float2bfloat16(v.z); cv.h[3] = __float2bfloat16(v.w);
    ((ushort4*)fb)[row * 64 + lane] = cv.u;
    float s = v.x * v.x + v.y * v.y + v.z * v.z + v.w * v.w;
#pragma unroll
    for (int off = 32; off; off >>= 1) s += __shfl_xor(s, off);
    if (lane == 0) {
        sq[row] = s;
        posmax[row] = 0u;
        negmin[row] = 0x7f800000u;   // +inf
    }
    if (blockIdx.x == 0 && threadIdx.x < 8) scalars[threadIdx.x] = 0.f;
}

// ---------------- kernel 1: pairwise mining via bf16 MFMA ----------------------
// Grid: 64 i-tiles x 8 j-chunks. Block 256 thr = 4 waves (2x2 of a 128x128 tile).
// A tile (128 rows x K=256) lives in REGISTERS (loaded once). B staged per jt
// into LDS via global_load_lds w/ source-side XOR swizzle. Labels have period
// 128 => positives are exactly the 128-tile diagonal (minus global self).
__global__ __launch_bounds__(256, 2)
void k_trip(const __hip_bfloat16* __restrict__ fb, const float* __restrict__ sq,
            unsigned* __restrict__ posmax, unsigned* __restrict__ negmin) {
    __shared__ uint4 Bs[4096];   // 128 cols x 32 granules (16B each) = 64 KB

    const int t = threadIdx.x;
    const int ib = (blockIdx.x >> 3) * 128;   // i-tile base row
    const int jc = (blockIdx.x & 7) * 1024;   // j-chunk base
    const int w = t >> 6, lane = t & 63;
    const int wi = w >> 1, wj = w & 1;
    const int quad = lane >> 4, l15 = lane & 15;

    // ---- A fragments in registers: rows wi*64 + ti*16 + l15, all K=256 ----
    short8 a[4][8];
#pragma unroll
    for (int ti = 0; ti < 4; ++ti) {
        const __hip_bfloat16* ap = fb + (size_t)(ib + wi * 64 + ti * 16 + l15) * C + quad * 8;
#pragma unroll
        for (int k = 0; k < 8; ++k)
            a[ti][k] = *(const short8*)(ap + k * 32);
    }

    // mining state: track m = (sj - 2*dot); add si at the end.
    float nm[16];                 // per acc-row running min over negatives
    float pm[4];                  // per ti running max over positives (diag)
#pragma unroll
    for (int q = 0; q < 16; ++q) nm[q] = INFINITY;
#pragma unroll
    for (int q = 0; q < 4; ++q) pm[q] = -INFINITY;

#pragma unroll 1
    for (int jt = 0; jt < 8; ++jt) {
        const int jb = jc + jt * 128;
        __syncthreads();                       // prior jt's LDS reads done
        // stage B tile (128 cols x 256 K bf16 = 64 KB), swizzled at the source:
        // LDS slot s holds granule (s&31) ^ (row&7) of row s>>5.
#pragma unroll
        for (int it = 0; it < 16; ++it) {
            int s = it * 256 + t;
            int srow = s >> 5, sg = s & 31;
            int g = sg ^ (srow & 7);
            async16(fb + (size_t)(jb + srow) * C + g * 8, &Bs[it * 256 + (t & ~63)]);
        }
        __syncthreads();                       // staging complete

#pragma unroll
        for (int tjh = 0; tjh < 2; ++tjh) {    // two half-j passes (acc = 32 regs)
            floatx4 acc[4][2];
#pragma unroll
            for (int ti = 0; ti < 4; ++ti)
#pragma unroll
                for (int tjj = 0; tjj < 2; ++tjj)
                    acc[ti][tjj] = (floatx4){0.f, 0.f, 0.f, 0.f};

#pragma unroll
            for (int k = 0; k < 8; ++k) {
                short8 b[2];
#pragma unroll
                for (int tjj = 0; tjj < 2; ++tjj) {
                    int col = wj * 64 + (tjh * 2 + tjj) * 16 + l15;
                    int g = k * 4 + quad;
                    b[tjj] = *(const short8*)&Bs[col * 32 + (g ^ (col & 7))];
                }
#pragma unroll
                for (int ti = 0; ti < 4; ++ti)
#pragma unroll
                    for (int tjj = 0; tjj < 2; ++tjj)
                        acc[ti][tjj] = __builtin_amdgcn_mfma_f32_16x16x32_bf16(
                            a[ti][k], b[tjj], acc[ti][tjj], 0, 0, 0);
            }

            // mining epilogue on m = sj - 2*dot
#pragma unroll
            for (int tjj = 0; tjj < 2; ++tjj) {
                int tj = tjh * 2 + tjj;
                int jjl = wj * 64 + tj * 16 + l15;
                float sj = sq[jb + jjl];
#pragma unroll
                for (int ti = 0; ti < 4; ++ti) {
                    bool diag_tile = (wi == wj) && (ti == tj);
#pragma unroll
                    for (int r = 0; r < 4; ++r) {
                        float v = fmaf(-2.f, acc[ti][tjj][r], sj);
                        if (diag_tile) {
                            bool isd = (l15 == quad * 4 + r);   // same label
                            nm[ti * 4 + r] = fminf(nm[ti * 4 + r], isd ? INFINITY : v);
                            if (jb != ib)                        // exclude global self
                                pm[ti] = fmaxf(pm[ti], isd ? v : -INFINITY);
                        } else {
                            nm[ti * 4 + r] = fminf(nm[ti * 4 + r], v);
                        }
                    }
                }
            }
        }
    }

    // ---- final: reduce nm across the 16 lanes of each quad; owner-lane pm ----
#pragma unroll
    for (int q = 0; q < 16; ++q) {
        float v = nm[q];
#pragma unroll
        for (int off = 1; off < 16; off <<= 1) v = fminf(v, __shfl_xor(v, off));
        if (l15 == 0) {
            int row = ib + wi * 64 + (q >> 2) * 16 + quad * 4 + (q & 3);
            float d2 = fmaxf(v + sq[row], 0.f);
            atomicMin(&negmin[row], __float_as_uint(d2));
        }
    }
    if (wi == wj && (l15 >> 2) == quad) {     // this lane owns the tile-diag elems
#pragma unroll
        for (int ti = 0; ti < 4; ++ti) {
            int row = ib + wi * 64 + ti * 16 + l15;
            float d2 = fmaxf(pm[ti] + sq[row], 0.f);
            atomicMax(&posmax[row], __float_as_uint(d2));
        }
    }
}

// ---------------- kernel 2: mse + dr (tiny reductions) -------------------------
__global__ void k_small(const float* __restrict__ s0, const float* __restrict__ s1,
                        const float* __restrict__ s2, const float* __restrict__ g,
                        const float* __restrict__ e0, const float* __restrict__ e1,
                        const float* __restrict__ l0, const float* __restrict__ l1,
                        float* __restrict__ scalars) {
    const int E = 64 * 1024;
    int tid = blockIdx.x * 256 + threadIdx.x;
    int nth = gridDim.x * 256;
    float acc = 0.f;
    for (int i = tid; i < E; i += nth) acc += fabsf(e0[i] - l0[i]) * (1.f / E);
    for (int i = tid; i < E; i += nth) acc += fabsf(e1[i] - l1[i]) * (1.f / E);
    if (tid < 192) {
        int k = tid >> 6, i = tid & 63;
        const float* s = (k == 0) ? s0 : ((k == 1) ? s1 : s2);
        float d = s[i] - g[i];
        acc += d * d * (1.f / 192.f);
    }
#pragma unroll
    for (int off = 32; off; off >>= 1) acc += __shfl_xor(acc, off);
    __shared__ float red[4];
    int lane = threadIdx.x & 63, wv = threadIdx.x >> 6;
    if (lane == 0) red[wv] = acc;
    __syncthreads();
    if (threadIdx.x == 0)
        atomicAdd(&scalars[0], red[0] + red[1] + red[2] + red[3]);
}

// ---------------- kernel 3: final combine ---------------------------------------
__global__ void k_final(const unsigned* __restrict__ posmax, const unsigned* __restrict__ negmin,
                        const float* __restrict__ scalars, float* __restrict__ out) {
    float acc = 0.f;
    for (int i = threadIdx.x; i < N; i += 1024) {
        float hp = sqrtf(__uint_as_float(posmax[i]));
        float hn = sqrtf(__uint_as_float(negmin[i]));
        acc += fmaxf(hp - hn + MARGIN, 0.f);
    }
#pragma unroll
    for (int off = 32; off; off >>= 1) acc += __shfl_xor(acc, off);
    __shared__ float red[16];
    if ((threadIdx.x & 63) == 0) red[threadIdx.x >> 6] = acc;
    __syncthreads();
    if (threadIdx.x == 0) {
        float tsum = 0.f;
#pragma unroll
        for (int i = 0; i < 16; ++i) tsum += red[i];
        out[0] = scalars[0] + tsum * (1.f / N);
    }
}

extern "C" void kernel_launch(void* const* d_in, const int* in_sizes, int n_in,
                              void* d_out, int out_size, void* d_ws, size_t ws_size,
                              hipStream_t stream) {
    const float* feat = (const float*)d_in[0];
    const float* gt   = (const float*)d_in[1];
    const float* s0   = (const float*)d_in[2];
    const float* s1   = (const float*)d_in[3];
    const float* s2   = (const float*)d_in[4];
    const float* e0   = (const float*)d_in[5];
    const float* e1   = (const float*)d_in[6];
    const float* l0   = (const float*)d_in[7];
    const float* l1   = (const float*)d_in[8];
    float* out = (float*)d_out;

    char* ws = (char*)d_ws;
    __hip_bfloat16* fb = (__hip_bfloat16*)ws;                       // 4 MB
    float*    sq      = (float*)(ws + (size_t)N * C * 2);
    unsigned* posmax  = (unsigned*)(ws + (size_t)N * C * 2 + N * 4);
    unsigned* negmin  = (unsigned*)(ws + (size_t)N * C * 2 + N * 8);
    float*    scalars = (float*)(ws + (size_t)N * C * 2 + N * 12);

    k_prep_sq<<<N / 4, 256, 0, stream>>>(feat, fb, sq, posmax, negmin, scalars);
    k_trip<<<512, 256, 0, stream>>>(fb, sq, posmax, negmin);
    k_small<<<64, 256, 0, stream>>>(s0, s1, s2, gt, e0, e1, l0, l1, scalars);
    k_final<<<1, 1024, 0, stream>>>(posmax, negmin, scalars, out);
}